// Round 25
// baseline (150.527 us; speedup 1.0000x reference)
//
#include <hip/hip_runtime.h>
#include <math.h>

#define BB 64
#define SS 512
#define HH 768
#define LL 21
#define STR 513              // eT row stride (odd -> conflict-free columns)
#define INFF __builtin_huge_valf()

__device__ inline float rlf(float v, int i) {
    return __int_as_float(__builtin_amdgcn_readlane(__float_as_int(v), i));
}
__device__ inline float mx3(float a, float b, float c) { return fmaxf(fmaxf(a, b), c); }
__device__ inline float wmax64(float v) {
    #pragma unroll
    for (int off = 32; off; off >>= 1) v = fmaxf(v, __shfl_xor(v, off));
    return v;
}
__device__ inline float rlmax21(float a) {
    float r0 = mx3(rlf(a, 0), rlf(a, 1), rlf(a, 2));
    float r1 = mx3(rlf(a, 3), rlf(a, 4), rlf(a, 5));
    float r2 = mx3(rlf(a, 6), rlf(a, 7), rlf(a, 8));
    float r3 = mx3(rlf(a, 9), rlf(a, 10), rlf(a, 11));
    float r4 = mx3(rlf(a, 12), rlf(a, 13), rlf(a, 14));
    float r5 = mx3(rlf(a, 15), rlf(a, 16), rlf(a, 17));
    float r6 = mx3(rlf(a, 18), rlf(a, 19), rlf(a, 20));
    return mx3(mx3(r0, r1, r2), mx3(r3, r4, r5), r6);
}

// ---------------- K1: emissions = hidden @ W + b (v14) ----------------
// 512 blocks x 128 thr; bid&3 = K-quarter (192 k); 2 rows/thread.
// DISTANCE-2 h prefetch (3 buffers): 2 loads in flight per row cover the
// ~900-cyc HBM latency under each 4-k compute window. Per-row k-order
// identical to v10/v13 -> bit-identical em.
__global__ __launch_bounds__(128) void k_emis(const float* __restrict__ hidden,
                                              const float* __restrict__ W,
                                              const float* __restrict__ bias,
                                              float* __restrict__ em0,
                                              float* __restrict__ em1,
                                              float* __restrict__ em2,
                                              float* __restrict__ em3) {
    __shared__ float Wl[192 * 24];       // 18432 B
    int tid = threadIdx.x;
    int q = blockIdx.x & 3;
    int rg = blockIdx.x >> 2;            // 0..127
    int rowA = rg * 256 + tid;
    int rowB = rowA + 128;
    const float* hpA = hidden + (size_t)rowA * HH + q * 192;
    const float* hpB = hidden + (size_t)rowB * HH + q * 192;
    const float4* Wq4 = reinterpret_cast<const float4*>(W + q * 192 * LL);

    for (int f = tid; f < 1008; f += 128) {
        float4 v = Wq4[f];
        int e0 = 4 * f;
        { int e = e0,     k = e / 21, l = e - 21 * k; Wl[k * 24 + l] = v.x; }
        { int e = e0 + 1, k = e / 21, l = e - 21 * k; Wl[k * 24 + l] = v.y; }
        { int e = e0 + 2, k = e / 21, l = e - 21 * k; Wl[k * 24 + l] = v.z; }
        { int e = e0 + 3, k = e / 21, l = e - 21 * k; Wl[k * 24 + l] = v.w; }
    }
    __syncthreads();

    float accA[LL], accB[LL];
    #pragma unroll
    for (int l = 0; l < LL; ++l) { accA[l] = 0.f; accB[l] = 0.f; }

#define FMA21R(ACC, HV) do { \
    float hv_ = (HV); \
    ACC[0]  = fmaf(hv_, q0.x, ACC[0]);  ACC[1]  = fmaf(hv_, q0.y, ACC[1]); \
    ACC[2]  = fmaf(hv_, q0.z, ACC[2]);  ACC[3]  = fmaf(hv_, q0.w, ACC[3]); \
    ACC[4]  = fmaf(hv_, q1.x, ACC[4]);  ACC[5]  = fmaf(hv_, q1.y, ACC[5]); \
    ACC[6]  = fmaf(hv_, q1.z, ACC[6]);  ACC[7]  = fmaf(hv_, q1.w, ACC[7]); \
    ACC[8]  = fmaf(hv_, q2.x, ACC[8]);  ACC[9]  = fmaf(hv_, q2.y, ACC[9]); \
    ACC[10] = fmaf(hv_, q2.z, ACC[10]); ACC[11] = fmaf(hv_, q2.w, ACC[11]); \
    ACC[12] = fmaf(hv_, q3.x, ACC[12]); ACC[13] = fmaf(hv_, q3.y, ACC[13]); \
    ACC[14] = fmaf(hv_, q3.z, ACC[14]); ACC[15] = fmaf(hv_, q3.w, ACC[15]); \
    ACC[16] = fmaf(hv_, q4.x, ACC[16]); ACC[17] = fmaf(hv_, q4.y, ACC[17]); \
    ACC[18] = fmaf(hv_, q4.z, ACC[18]); ACC[19] = fmaf(hv_, q4.w, ACC[19]); \
    ACC[20] = fmaf(hv_, q20, ACC[20]); } while (0)

    float4 h0A = *reinterpret_cast<const float4*>(hpA);
    float4 h0B = *reinterpret_cast<const float4*>(hpB);
    float4 h1A = *reinterpret_cast<const float4*>(hpA + 4);
    float4 h1B = *reinterpret_cast<const float4*>(hpB + 4);
    for (int c = 0; c < 48; ++c) {
        float4 h2A = h1A, h2B = h1B;
        if (c + 2 < 48) {
            h2A = *reinterpret_cast<const float4*>(hpA + (c + 2) * 4);
            h2B = *reinterpret_cast<const float4*>(hpB + (c + 2) * 4);
        }
        const float* wb = Wl + (c * 4) * 24;
        #pragma unroll
        for (int e = 0; e < 4; ++e) {
            const float* w = wb + e * 24;
            float4 q0 = *reinterpret_cast<const float4*>(w);
            float4 q1 = *reinterpret_cast<const float4*>(w + 4);
            float4 q2 = *reinterpret_cast<const float4*>(w + 8);
            float4 q3 = *reinterpret_cast<const float4*>(w + 12);
            float4 q4 = *reinterpret_cast<const float4*>(w + 16);
            float q20 = w[20];
            float hA = (e == 0) ? h0A.x : (e == 1) ? h0A.y : (e == 2) ? h0A.z : h0A.w;
            float hB = (e == 0) ? h0B.x : (e == 1) ? h0B.y : (e == 2) ? h0B.z : h0B.w;
            FMA21R(accA, hA);
            FMA21R(accB, hB);
        }
        h0A = h1A; h0B = h1B;
        h1A = h2A; h1B = h2B;
    }
#undef FMA21R

    float* emq = (q == 0 ? em0 : q == 1 ? em1 : q == 2 ? em2 : em3);
    float* emrA = emq + (size_t)rowA * LL;
    float* emrB = emq + (size_t)rowB * LL;
    if (q == 0) {
        #pragma unroll
        for (int l = 0; l < LL; ++l) { emrA[l] = accA[l] + bias[l]; emrB[l] = accB[l] + bias[l]; }
    } else {
        #pragma unroll
        for (int l = 0; l < LL; ++l) { emrA[l] = accA[l]; emrB[l] = accB[l]; }
    }
}

// ---------------- K2: fused scan dispatch (R21/R24 core) ----------------
// blocks 0-63: Viterbi fwd (S -> Sout [b][j][t]); 64-127: LSE fwd; 128-191: numerator.
__global__ __launch_bounds__(64) void k_scan(const float* __restrict__ em0,
                                             const float* __restrict__ em1,
                                             const float* __restrict__ em2,
                                             const float* __restrict__ em3,
                                             const int* __restrict__ attn,
                                             const int* __restrict__ labels,
                                             const float* __restrict__ startT,
                                             const float* __restrict__ endT,
                                             const float* __restrict__ trans,
                                             float* __restrict__ num,
                                             float* __restrict__ denom,
                                             float* __restrict__ Sout) {
    __shared__ float eLT[LL * STR + 8];
    int lane = threadIdx.x;
    int bid = blockIdx.x;
    bool act = lane < LL;
    int jj = act ? lane : (LL - 1);

    if (bid < 128) {
        int b = bid & 63;
        size_t boff = (size_t)b * SS * LL;
        const float* emb0 = em0 + boff;
        const float* emb1 = em1 + boff;
        const float* emb2 = em2 + boff;
        const float* emb3 = em3 + boff;
        const int* mrow = attn + b * SS;

        for (int f = lane; f < (SS * LL) / 4; f += 64) {
            float4 v0 = *reinterpret_cast<const float4*>(emb0 + 4 * f);
            float4 v1 = *reinterpret_cast<const float4*>(emb1 + 4 * f);
            float4 v2 = *reinterpret_cast<const float4*>(emb2 + 4 * f);
            float4 v3 = *reinterpret_cast<const float4*>(emb3 + 4 * f);
            float4 v = make_float4((v0.x + v1.x) + (v2.x + v3.x),
                                   (v0.y + v1.y) + (v2.y + v3.y),
                                   (v0.z + v1.z) + (v2.z + v3.z),
                                   (v0.w + v1.w) + (v2.w + v3.w));
            unsigned e0 = 4u * (unsigned)f;
            { unsigned t = e0 / 21u,       j = e0 - 21u * t;       eLT[j * STR + t] = v.x; }
            { unsigned e = e0 + 1, t = e / 21u, j = e - 21u * t;   eLT[j * STR + t] = v.y; }
            { unsigned e = e0 + 2, t = e / 21u, j = e - 21u * t;   eLT[j * STR + t] = v.z; }
            { unsigned e = e0 + 3, t = e / 21u, j = e - 21u * t;   eLT[j * STR + t] = v.w; }
        }
        __syncthreads();

        int jbase = jj * STR;
        float A0, A1, A2, A3, B0, B1, B2, B3;

#define LDG(P, G) do { int t4_ = (G) * 4; \
    P##0 = eLT[jbase + t4_];     P##1 = eLT[jbase + t4_ + 1]; \
    P##2 = eLT[jbase + t4_ + 2]; P##3 = eLT[jbase + t4_ + 3]; } while (0)

        if (bid < 64) {
            // ---------------- Viterbi ----------------
            float Tc[LL];
            #pragma unroll
            for (int i = 0; i < LL; ++i) Tc[i] = trans[i * LL + jj];
            float* Sgj = Sout + (size_t)b * (LL * SS) + jj * SS;

#define VCORE(EMIT, BIT) do { \
    float sv_[LL]; \
    _Pragma("unroll") for (int i_ = 0; i_ < LL; ++i_) sv_[i_] = rlf(a, i_); \
    float cd_[LL]; \
    _Pragma("unroll") for (int i_ = 0; i_ < LL; ++i_) cd_[i_] = sv_[i_] + Tc[i_]; \
    float x0 = mx3(cd_[0], cd_[1], cd_[2]),   x1 = mx3(cd_[3], cd_[4], cd_[5]); \
    float x2 = mx3(cd_[6], cd_[7], cd_[8]),   x3 = mx3(cd_[9], cd_[10], cd_[11]); \
    float x4 = mx3(cd_[12], cd_[13], cd_[14]), x5 = mx3(cd_[15], cd_[16], cd_[17]); \
    float x6 = mx3(cd_[18], cd_[19], cd_[20]); \
    float best = mx3(mx3(x0, x1, x2), mx3(x3, x4, x5), x6); \
    bool mt_ = ((mm >> (BIT)) & 1ull) != 0ull; \
    float an_ = best + (EMIT); \
    a = (mt_ && act) ? an_ : a; \
} while (0)
#define VGROUPR(P, TB, BB0) do { \
    float o0_, o1_, o2_, o3_; \
    VCORE(P##0, (BB0));     o0_ = a; \
    VCORE(P##1, (BB0) + 1); o1_ = a; \
    VCORE(P##2, (BB0) + 2); o2_ = a; \
    VCORE(P##3, (BB0) + 3); o3_ = a; \
    if (act) *reinterpret_cast<float4*>(Sgj + (TB)) = make_float4(o0_, o1_, o2_, o3_); \
} while (0)

            LDG(A, 0); LDG(B, 1);
            int mk0 = mrow[lane];
            unsigned long long mm = __ballot(mk0 != 0);
            mk0 = mrow[64 + lane];
            float a = act ? (startT[lane] + A0) : -INFF;
            // peel gg = 0 (steps 1..7)
            {
                float o0_ = a, o1_, o2_, o3_;
                VCORE(A1, 1); o1_ = a;
                VCORE(A2, 2); o2_ = a;
                VCORE(A3, 3); o3_ = a;
                if (act) *reinterpret_cast<float4*>(Sgj) = make_float4(o0_, o1_, o2_, o3_);
                LDG(A, 2);
                VGROUPR(B, 4, 4);
                LDG(B, 3);
            }
            for (int gg = 1; gg < 64; ++gg) {
                if ((gg & 7) == 0) {
                    mm = __ballot(mk0 != 0);
                    if (gg != 56) mk0 = mrow[((gg >> 3) + 1) * 64 + lane];
                }
                int bb = (gg & 7) * 8;
                VGROUPR(A, 8 * gg, bb);
                LDG(A, 2 * gg + 2);
                VGROUPR(B, 8 * gg + 4, bb + 4);
                LDG(B, 2 * gg + 3);
            }
#undef VCORE
#undef VGROUPR
        } else {
            // ---------------- LSE forward (exp-trick, batched readlanes) ----
            float Ec[LL];
            #pragma unroll
            for (int i = 0; i < LL; ++i) Ec[i] = __expf(trans[i * LL + jj]);

#define LCORE(EMIT, BIT) do { \
    float x_ = __expf(a - M); \
    float sv_[LL]; \
    _Pragma("unroll") for (int i_ = 0; i_ < LL; ++i_) sv_[i_] = rlf(x_, i_); \
    float g0_ = sv_[0] * Ec[0]; \
    _Pragma("unroll") for (int i_ = 1; i_ < 7; ++i_)  g0_ = fmaf(sv_[i_], Ec[i_], g0_); \
    float g1_ = sv_[7] * Ec[7]; \
    _Pragma("unroll") for (int i_ = 8; i_ < 14; ++i_) g1_ = fmaf(sv_[i_], Ec[i_], g1_); \
    float g2_ = sv_[14] * Ec[14]; \
    _Pragma("unroll") for (int i_ = 15; i_ < 21; ++i_) g2_ = fmaf(sv_[i_], Ec[i_], g2_); \
    float Ss_ = (g0_ + g1_) + g2_; \
    bool mt_ = ((mm >> (BIT)) & 1ull) != 0ull; \
    float an_ = M + __logf(Ss_) + (EMIT); \
    a = (mt_ && act) ? an_ : a; \
} while (0)

            LDG(A, 0); LDG(B, 1);
            int mk0 = mrow[lane];
            unsigned long long mm = __ballot(mk0 != 0);
            mk0 = mrow[64 + lane];
            float a = act ? (startT[lane] + A0) : -INFF;
            float M = rlmax21(a);
            // peel gg = 0 (steps 1..7)
            {
                LCORE(A1, 1); LCORE(A2, 2); LCORE(A3, 3);
                LDG(A, 2);
                LCORE(B0, 4); LCORE(B1, 5); LCORE(B2, 6); LCORE(B3, 7);
                LDG(B, 3);
            }
            for (int gg = 1; gg < 64; ++gg) {
                if ((gg & 7) == 0) {
                    mm = __ballot(mk0 != 0);
                    if (gg != 56) mk0 = mrow[((gg >> 3) + 1) * 64 + lane];
                }
                M = rlmax21(a);
                int bb = (gg & 7) * 8;
                LCORE(A0, bb);     LCORE(A1, bb + 1); LCORE(A2, bb + 2); LCORE(A3, bb + 3);
                LDG(A, 2 * gg + 2);
                LCORE(B0, bb + 4); LCORE(B1, bb + 5); LCORE(B2, bb + 6); LCORE(B3, bb + 7);
                LDG(B, 2 * gg + 3);
            }
#undef LCORE
            float f = act ? (a + endT[lane]) : -INFF;
            float m = wmax64(f);
            float p = act ? __expf(f - m) : 0.f;
            #pragma unroll
            for (int off = 32; off; off >>= 1) p += __shfl_xor(p, off);
            if (lane == 0) denom[b] = m + __logf(p);
        }
#undef LDG
    } else {
        // ---------------- numerator ----------------
        int b = bid - 128;
        const int* lrow = labels + b * SS;
        const int* arow = attn + b * SS;
        float psum = 0.f;
        int pcnt = 0;
        for (int s = 0; s < 8; ++s) {
            int t = s * 64 + lane;
            int lab = lrow[t];
            int mk = arow[t];
            int valid = (t == 0) ? 1 : ((mk != 0 && lab >= 0) ? 1 : 0);
            if (t >= 1 && valid) {
                int tag = (lab < 0) ? 0 : lab;
                int labp = lrow[t - 1];
                int tagp = (t == 1) ? 0 : ((labp < 0) ? 0 : labp);
                size_t ei = ((size_t)b * SS + t) * LL + tag;
                psum += trans[tagp * LL + tag] + ((em0[ei] + em1[ei]) + (em2[ei] + em3[ei]));
            }
            pcnt += valid;
        }
        #pragma unroll
        for (int off = 32; off; off >>= 1) {
            psum += __shfl_xor(psum, off);
            pcnt += __shfl_xor(pcnt, off);
        }
        int ts = pcnt - 1;
        int labL = lrow[ts];
        int tagL = (ts == 0) ? 0 : ((labL < 0) ? 0 : labL);
        if (lane == 0) {
            size_t e0i = (size_t)b * SS * LL;
            num[b] = startT[0] + ((em0[e0i] + em1[e0i]) + (em2[e0i] + em3[e0i]))
                   + psum + endT[tagL];
        }
    }
}

// ---------------- K3: backtrack + FUSED one-hot logits + loss ----------------
__global__ __launch_bounds__(512) void k_back(const float* __restrict__ S,
                                              const int* __restrict__ attn,
                                              const float* __restrict__ endT,
                                              const float* __restrict__ trans,
                                              const float* __restrict__ num,
                                              const float* __restrict__ denom,
                                              float* __restrict__ out) {
    __shared__ float Sl[LL][517];             // 43428 B
    __shared__ unsigned char pred[SS * 24];   // 12288 B
    __shared__ unsigned char mapL[64 * 32];   // 2048 B
    __shared__ float Tl[441];                 // 1764 B
    __shared__ int tg_s[SS];                  // 2048 B
    int tid = threadIdx.x, b = blockIdx.x;
    const float* SB = S + (size_t)b * (LL * SS);
    for (int i = tid; i < 441; i += 512) Tl[i] = trans[i];
    for (int f = tid; f < (LL * SS) / 4; f += 512) {
        float4 v = *reinterpret_cast<const float4*>(SB + 4 * f);
        int j = f >> 7, t0 = (f & 127) * 4;
        Sl[j][t0] = v.x; Sl[j][t0 + 1] = v.y; Sl[j][t0 + 2] = v.z; Sl[j][t0 + 3] = v.w;
    }
    if (b == 0 && tid < 64) {
        float llh = num[tid] - denom[tid];
        #pragma unroll
        for (int off = 32; off; off >>= 1) llh += __shfl_xor(llh, off);
        if (tid == 0) out[0] = -llh / (float)BB;
    }
    __syncthreads();

    for (int u = tid; u < 511 * LL; u += 512) {
        int t = 1 + u / LL;
        int j = u - (u / LL) * LL;
        unsigned int pj = (unsigned int)j;
        if (attn[b * SS + t] != 0) {
            float bv = Sl[0][t - 1] + Tl[j];
            unsigned int bi = 0;
            #pragma unroll
            for (int i = 1; i < LL; ++i) {
                float c = Sl[i][t - 1] + Tl[i * LL + j];
                bool g = c > bv;            // strict > : first max wins
                bv = g ? c : bv;
                bi = g ? (unsigned int)i : bi;
            }
            pj = bi;
        }
        pred[t * 24 + j] = (unsigned char)pj;
    }
    __syncthreads();

    if (tid < 64) {
        int lane = tid;
        float f = (lane < LL) ? (Sl[lane][SS - 1] + endT[lane]) : -INFF;
        float m = wmax64(f);
        unsigned long long msk = __ballot(f == m);
        int best_last = __ffsll(msk) - 1;

        int tlo = 8 * lane + 1;
        int thi = 8 * lane + 8; if (thi > 511) thi = 511;
        unsigned int BM[LL];
        #pragma unroll
        for (int s = 0; s < LL; ++s) BM[s] = s;
        for (int k = 0; k < 8; ++k) {
            int t = thi - k;
            if (t >= tlo) {
                #pragma unroll
                for (int s = 0; s < LL; ++s) BM[s] = pred[t * 24 + BM[s]];
            }
        }
        #pragma unroll
        for (int s = 0; s < LL; ++s) mapL[lane * 32 + s] = (unsigned char)BM[s];

        #pragma unroll
        for (int kk = 1; kk < 64; kk <<= 1) {
            int p = lane + kk;
            bool vld = p < 64;
            int pp = vld ? p : 0;
            unsigned int P[LL];
            #pragma unroll
            for (int s = 0; s < LL; ++s) {
                unsigned int v = mapL[pp * 32 + s];
                P[s] = vld ? v : (unsigned int)s;
            }
            unsigned int N[LL];
            #pragma unroll
            for (int s = 0; s < LL; ++s) N[s] = mapL[lane * 32 + P[s]];
            #pragma unroll
            for (int s = 0; s < LL; ++s) mapL[lane * 32 + s] = (unsigned char)N[s];
        }

        int st8 = mapL[lane * 32 + best_last];
        int nxt = __shfl(st8, lane + 1);
        int cur = (lane == 63) ? best_last : nxt;
        for (int k = 0; k < 8; ++k) {
            int t = thi - k;
            if (t >= tlo) {
                tg_s[t] = cur;
                cur = pred[t * 24 + cur];
            }
        }
        if (lane == 0) tg_s[0] = cur;
    }
    __syncthreads();

    {
        int t = tid;
        int tag = tg_s[t];
        int mk = attn[b * SS + t];
        float* o = out + 1 + ((size_t)b * SS + t) * LL;
        #pragma unroll
        for (int l = 0; l < LL; ++l) o[l] = (mk && tag == l) ? 1.f : 0.f;
    }
}

extern "C" void kernel_launch(void* const* d_in, const int* in_sizes, int n_in,
                              void* d_out, int out_size, void* d_ws, size_t ws_size,
                              hipStream_t stream) {
    const float* hidden = (const float*)d_in[0];
    const int*   attn   = (const int*)d_in[1];
    const int*   labels = (const int*)d_in[2];
    const float* W      = (const float*)d_in[3];
    const float* bias   = (const float*)d_in[4];
    const float* startT = (const float*)d_in[5];
    const float* endT   = (const float*)d_in[6];
    const float* trans  = (const float*)d_in[7];
    float* out = (float*)d_out;

    float* wsf   = (float*)d_ws;
    size_t emsz  = (size_t)BB * SS * LL;
    float* em0   = wsf;
    float* em1   = em0 + emsz;
    float* em2   = em1 + emsz;
    float* em3   = em2 + emsz;
    float* num   = em3 + emsz;
    float* denom = num + 64;
    float* Sbuf  = out + 4;                   // 16B-aligned; overwritten by k_back

    hipLaunchKernelGGL(k_emis, dim3(512),  dim3(128), 0, stream, hidden, W, bias,
                       em0, em1, em2, em3);
    hipLaunchKernelGGL(k_scan, dim3(192), dim3(64),  0, stream, em0, em1, em2, em3,
                       attn, labels, startT, endT, trans, num, denom, Sbuf);
    hipLaunchKernelGGL(k_back, dim3(64),  dim3(512), 0, stream, Sbuf, attn, endT, trans,
                       num, denom, out);
}

// Round 26
// 146.284 us; speedup vs baseline: 1.0290x; 1.0290x over previous
//
#include <hip/hip_runtime.h>
#include <math.h>

#define BB 64
#define SS 512
#define HH 768
#define LL 21
#define STR 513              // eT row stride (odd -> conflict-free columns)
#define INFF __builtin_huge_valf()

__device__ inline float rlf(float v, int i) {
    return __int_as_float(__builtin_amdgcn_readlane(__float_as_int(v), i));
}
__device__ inline float mx3(float a, float b, float c) { return fmaxf(fmaxf(a, b), c); }
__device__ inline float wmax64(float v) {
    #pragma unroll
    for (int off = 32; off; off >>= 1) v = fmaxf(v, __shfl_xor(v, off));
    return v;
}
__device__ inline float rlmax21(float a) {
    float r0 = mx3(rlf(a, 0), rlf(a, 1), rlf(a, 2));
    float r1 = mx3(rlf(a, 3), rlf(a, 4), rlf(a, 5));
    float r2 = mx3(rlf(a, 6), rlf(a, 7), rlf(a, 8));
    float r3 = mx3(rlf(a, 9), rlf(a, 10), rlf(a, 11));
    float r4 = mx3(rlf(a, 12), rlf(a, 13), rlf(a, 14));
    float r5 = mx3(rlf(a, 15), rlf(a, 16), rlf(a, 17));
    float r6 = mx3(rlf(a, 18), rlf(a, 19), rlf(a, 20));
    return mx3(mx3(r0, r1, r2), mx3(r3, r4, r5), r6);
}

// ---------------- K1: emissions = hidden @ W + b (v10, best measured) ------
// 1024 blocks x 128 thr. bid&3 = K-quarter (192 k); bid>>2 -> 128 rows;
// thread = row. W-quarter staged once to LDS [192][24] (18.4KB -> 4 blocks/CU
// = 2 waves/SIMD). Per-k W reads are wave-broadcast. Partial em -> emQ[q].
__global__ __launch_bounds__(128) void k_emis(const float* __restrict__ hidden,
                                              const float* __restrict__ W,
                                              const float* __restrict__ bias,
                                              float* __restrict__ em0,
                                              float* __restrict__ em1,
                                              float* __restrict__ em2,
                                              float* __restrict__ em3) {
    __shared__ float Wl[192 * 24];       // 18432 B
    int tid = threadIdx.x;
    int q = blockIdx.x & 3;
    int rg = blockIdx.x >> 2;
    int row = rg * 128 + tid;
    const float* hp = hidden + (size_t)row * HH + q * 192;
    const float4* Wq4 = reinterpret_cast<const float4*>(W + q * 192 * LL);

    for (int f = tid; f < 1008; f += 128) {
        float4 v = Wq4[f];
        int e0 = 4 * f;
        { int e = e0,     k = e / 21, l = e - 21 * k; Wl[k * 24 + l] = v.x; }
        { int e = e0 + 1, k = e / 21, l = e - 21 * k; Wl[k * 24 + l] = v.y; }
        { int e = e0 + 2, k = e / 21, l = e - 21 * k; Wl[k * 24 + l] = v.z; }
        { int e = e0 + 3, k = e / 21, l = e - 21 * k; Wl[k * 24 + l] = v.w; }
    }
    __syncthreads();

    float acc[LL];
    #pragma unroll
    for (int l = 0; l < LL; ++l) acc[l] = 0.f;

#define FMAK(HV, WB) do { \
    float hv_ = (HV); \
    float4 q0 = *reinterpret_cast<const float4*>(WB); \
    float4 q1 = *reinterpret_cast<const float4*>((WB) + 4); \
    float4 q2 = *reinterpret_cast<const float4*>((WB) + 8); \
    float4 q3 = *reinterpret_cast<const float4*>((WB) + 12); \
    float4 q4 = *reinterpret_cast<const float4*>((WB) + 16); \
    float q20 = (WB)[20]; \
    acc[0]  = fmaf(hv_, q0.x, acc[0]);  acc[1]  = fmaf(hv_, q0.y, acc[1]); \
    acc[2]  = fmaf(hv_, q0.z, acc[2]);  acc[3]  = fmaf(hv_, q0.w, acc[3]); \
    acc[4]  = fmaf(hv_, q1.x, acc[4]);  acc[5]  = fmaf(hv_, q1.y, acc[5]); \
    acc[6]  = fmaf(hv_, q1.z, acc[6]);  acc[7]  = fmaf(hv_, q1.w, acc[7]); \
    acc[8]  = fmaf(hv_, q2.x, acc[8]);  acc[9]  = fmaf(hv_, q2.y, acc[9]); \
    acc[10] = fmaf(hv_, q2.z, acc[10]); acc[11] = fmaf(hv_, q2.w, acc[11]); \
    acc[12] = fmaf(hv_, q3.x, acc[12]); acc[13] = fmaf(hv_, q3.y, acc[13]); \
    acc[14] = fmaf(hv_, q3.z, acc[14]); acc[15] = fmaf(hv_, q3.w, acc[15]); \
    acc[16] = fmaf(hv_, q4.x, acc[16]); acc[17] = fmaf(hv_, q4.y, acc[17]); \
    acc[18] = fmaf(hv_, q4.z, acc[18]); acc[19] = fmaf(hv_, q4.w, acc[19]); \
    acc[20] = fmaf(hv_, q20, acc[20]); } while (0)

    float4 ha = *reinterpret_cast<const float4*>(hp);
    for (int c = 0; c < 48; ++c) {
        float4 hn = ha;
        if (c + 1 < 48) hn = *reinterpret_cast<const float4*>(hp + (c + 1) * 4);
        const float* wb = Wl + (c * 4) * 24;
        FMAK(ha.x, wb);
        FMAK(ha.y, wb + 24);
        FMAK(ha.z, wb + 48);
        FMAK(ha.w, wb + 72);
        ha = hn;
    }
#undef FMAK

    float* emr = (q == 0 ? em0 : q == 1 ? em1 : q == 2 ? em2 : em3) + (size_t)row * LL;
    if (q == 0) {
        #pragma unroll
        for (int l = 0; l < LL; ++l) emr[l] = acc[l] + bias[l];
    } else {
        #pragma unroll
        for (int l = 0; l < LL; ++l) emr[l] = acc[l];
    }
}

// ---------------- K2: fused scan dispatch ----------------
// blocks 0-63: Viterbi fwd (S -> Sout [b][j][t]); 64-127: LSE fwd; 128-191: numerator.
__global__ __launch_bounds__(64) void k_scan(const float* __restrict__ em0,
                                             const float* __restrict__ em1,
                                             const float* __restrict__ em2,
                                             const float* __restrict__ em3,
                                             const int* __restrict__ attn,
                                             const int* __restrict__ labels,
                                             const float* __restrict__ startT,
                                             const float* __restrict__ endT,
                                             const float* __restrict__ trans,
                                             float* __restrict__ num,
                                             float* __restrict__ denom,
                                             float* __restrict__ Sout) {
    __shared__ float eLT[LL * STR + 8];
    int lane = threadIdx.x;
    int bid = blockIdx.x;
    bool act = lane < LL;
    int jj = act ? lane : (LL - 1);

    if (bid < 128) {
        int b = bid & 63;
        size_t boff = (size_t)b * SS * LL;
        const float* emb0 = em0 + boff;
        const float* emb1 = em1 + boff;
        const float* emb2 = em2 + boff;
        const float* emb3 = em3 + boff;
        const int* mrow = attn + b * SS;

        for (int f = lane; f < (SS * LL) / 4; f += 64) {
            float4 v0 = *reinterpret_cast<const float4*>(emb0 + 4 * f);
            float4 v1 = *reinterpret_cast<const float4*>(emb1 + 4 * f);
            float4 v2 = *reinterpret_cast<const float4*>(emb2 + 4 * f);
            float4 v3 = *reinterpret_cast<const float4*>(emb3 + 4 * f);
            float4 v = make_float4((v0.x + v1.x) + (v2.x + v3.x),
                                   (v0.y + v1.y) + (v2.y + v3.y),
                                   (v0.z + v1.z) + (v2.z + v3.z),
                                   (v0.w + v1.w) + (v2.w + v3.w));
            unsigned e0 = 4u * (unsigned)f;
            { unsigned t = e0 / 21u,       j = e0 - 21u * t;       eLT[j * STR + t] = v.x; }
            { unsigned e = e0 + 1, t = e / 21u, j = e - 21u * t;   eLT[j * STR + t] = v.y; }
            { unsigned e = e0 + 2, t = e / 21u, j = e - 21u * t;   eLT[j * STR + t] = v.z; }
            { unsigned e = e0 + 3, t = e / 21u, j = e - 21u * t;   eLT[j * STR + t] = v.w; }
        }
        __syncthreads();

        int jbase = jj * STR;
        float A0, A1, A2, A3, B0, B1, B2, B3;

#define LDG(P, G) do { int t4_ = (G) * 4; \
    P##0 = eLT[jbase + t4_];     P##1 = eLT[jbase + t4_ + 1]; \
    P##2 = eLT[jbase + t4_ + 2]; P##3 = eLT[jbase + t4_ + 3]; } while (0)

        if (bid < 64) {
            // ---------------- Viterbi ----------------
            float Tc[LL];
            #pragma unroll
            for (int i = 0; i < LL; ++i) Tc[i] = trans[i * LL + jj];
            float* Sgj = Sout + (size_t)b * (LL * SS) + jj * SS;

#define VCORE(EMIT, BIT) do { \
    float sv_[LL]; \
    _Pragma("unroll") for (int i_ = 0; i_ < LL; ++i_) sv_[i_] = rlf(a, i_); \
    float cd_[LL]; \
    _Pragma("unroll") for (int i_ = 0; i_ < LL; ++i_) cd_[i_] = sv_[i_] + Tc[i_]; \
    float x0 = mx3(cd_[0], cd_[1], cd_[2]),   x1 = mx3(cd_[3], cd_[4], cd_[5]); \
    float x2 = mx3(cd_[6], cd_[7], cd_[8]),   x3 = mx3(cd_[9], cd_[10], cd_[11]); \
    float x4 = mx3(cd_[12], cd_[13], cd_[14]), x5 = mx3(cd_[15], cd_[16], cd_[17]); \
    float x6 = mx3(cd_[18], cd_[19], cd_[20]); \
    float best = mx3(mx3(x0, x1, x2), mx3(x3, x4, x5), x6); \
    bool mt_ = ((mm >> (BIT)) & 1ull) != 0ull; \
    float an_ = best + (EMIT); \
    a = (mt_ && act) ? an_ : a; \
} while (0)
#define VGROUPR(P, TB, BB0) do { \
    float o0_, o1_, o2_, o3_; \
    VCORE(P##0, (BB0));     o0_ = a; \
    VCORE(P##1, (BB0) + 1); o1_ = a; \
    VCORE(P##2, (BB0) + 2); o2_ = a; \
    VCORE(P##3, (BB0) + 3); o3_ = a; \
    if (act) *reinterpret_cast<float4*>(Sgj + (TB)) = make_float4(o0_, o1_, o2_, o3_); \
} while (0)

            LDG(A, 0); LDG(B, 1);
            int mk0 = mrow[lane];
            unsigned long long mm = __ballot(mk0 != 0);
            mk0 = mrow[64 + lane];
            float a = act ? (startT[lane] + A0) : -INFF;
            // peel gg = 0 (steps 1..7)
            {
                float o0_ = a, o1_, o2_, o3_;
                VCORE(A1, 1); o1_ = a;
                VCORE(A2, 2); o2_ = a;
                VCORE(A3, 3); o3_ = a;
                if (act) *reinterpret_cast<float4*>(Sgj) = make_float4(o0_, o1_, o2_, o3_);
                LDG(A, 2);
                VGROUPR(B, 4, 4);
                LDG(B, 3);
            }
            for (int gg = 1; gg < 64; ++gg) {
                if ((gg & 7) == 0) {
                    mm = __ballot(mk0 != 0);
                    if (gg != 56) mk0 = mrow[((gg >> 3) + 1) * 64 + lane];
                }
                int bb = (gg & 7) * 8;
                VGROUPR(A, 8 * gg, bb);
                LDG(A, 2 * gg + 2);
                VGROUPR(B, 8 * gg + 4, bb + 4);
                LDG(B, 2 * gg + 3);
            }
#undef VCORE
#undef VGROUPR
        } else {
            // ---------------- LSE forward (exp-trick, batched readlanes) ----
            float Ec[LL];
            #pragma unroll
            for (int i = 0; i < LL; ++i) Ec[i] = __expf(trans[i * LL + jj]);

#define LCORE(EMIT, BIT) do { \
    float x_ = __expf(a - M); \
    float sv_[LL]; \
    _Pragma("unroll") for (int i_ = 0; i_ < LL; ++i_) sv_[i_] = rlf(x_, i_); \
    float g0_ = sv_[0] * Ec[0]; \
    _Pragma("unroll") for (int i_ = 1; i_ < 7; ++i_)  g0_ = fmaf(sv_[i_], Ec[i_], g0_); \
    float g1_ = sv_[7] * Ec[7]; \
    _Pragma("unroll") for (int i_ = 8; i_ < 14; ++i_) g1_ = fmaf(sv_[i_], Ec[i_], g1_); \
    float g2_ = sv_[14] * Ec[14]; \
    _Pragma("unroll") for (int i_ = 15; i_ < 21; ++i_) g2_ = fmaf(sv_[i_], Ec[i_], g2_); \
    float Ss_ = (g0_ + g1_) + g2_; \
    bool mt_ = ((mm >> (BIT)) & 1ull) != 0ull; \
    float an_ = M + __logf(Ss_) + (EMIT); \
    a = (mt_ && act) ? an_ : a; \
} while (0)

            LDG(A, 0); LDG(B, 1);
            int mk0 = mrow[lane];
            unsigned long long mm = __ballot(mk0 != 0);
            mk0 = mrow[64 + lane];
            float a = act ? (startT[lane] + A0) : -INFF;
            float M = rlmax21(a);
            // peel gg = 0 (steps 1..7)
            {
                LCORE(A1, 1); LCORE(A2, 2); LCORE(A3, 3);
                LDG(A, 2);
                LCORE(B0, 4); LCORE(B1, 5); LCORE(B2, 6); LCORE(B3, 7);
                LDG(B, 3);
            }
            for (int gg = 1; gg < 64; ++gg) {
                if ((gg & 7) == 0) {
                    mm = __ballot(mk0 != 0);
                    if (gg != 56) mk0 = mrow[((gg >> 3) + 1) * 64 + lane];
                }
                M = rlmax21(a);
                int bb = (gg & 7) * 8;
                LCORE(A0, bb);     LCORE(A1, bb + 1); LCORE(A2, bb + 2); LCORE(A3, bb + 3);
                LDG(A, 2 * gg + 2);
                LCORE(B0, bb + 4); LCORE(B1, bb + 5); LCORE(B2, bb + 6); LCORE(B3, bb + 7);
                LDG(B, 2 * gg + 3);
            }
#undef LCORE
            float f = act ? (a + endT[lane]) : -INFF;
            float m = wmax64(f);
            float p = act ? __expf(f - m) : 0.f;
            #pragma unroll
            for (int off = 32; off; off >>= 1) p += __shfl_xor(p, off);
            if (lane == 0) denom[b] = m + __logf(p);
        }
#undef LDG
    } else {
        // ---------------- numerator ----------------
        int b = bid - 128;
        const int* lrow = labels + b * SS;
        const int* arow = attn + b * SS;
        float psum = 0.f;
        int pcnt = 0;
        for (int s = 0; s < 8; ++s) {
            int t = s * 64 + lane;
            int lab = lrow[t];
            int mk = arow[t];
            int valid = (t == 0) ? 1 : ((mk != 0 && lab >= 0) ? 1 : 0);
            if (t >= 1 && valid) {
                int tag = (lab < 0) ? 0 : lab;
                int labp = lrow[t - 1];
                int tagp = (t == 1) ? 0 : ((labp < 0) ? 0 : labp);
                size_t ei = ((size_t)b * SS + t) * LL + tag;
                psum += trans[tagp * LL + tag] + ((em0[ei] + em1[ei]) + (em2[ei] + em3[ei]));
            }
            pcnt += valid;
        }
        #pragma unroll
        for (int off = 32; off; off >>= 1) {
            psum += __shfl_xor(psum, off);
            pcnt += __shfl_xor(pcnt, off);
        }
        int ts = pcnt - 1;
        int labL = lrow[ts];
        int tagL = (ts == 0) ? 0 : ((labL < 0) ? 0 : labL);
        if (lane == 0) {
            size_t e0i = (size_t)b * SS * LL;
            num[b] = startT[0] + ((em0[e0i] + em1[e0i]) + (em2[e0i] + em3[e0i]))
                   + psum + endT[tagL];
        }
    }
}

// ---------------- K3: backtrack + FUSED one-hot logits + loss ----------------
__global__ __launch_bounds__(512) void k_back(const float* __restrict__ S,
                                              const int* __restrict__ attn,
                                              const float* __restrict__ endT,
                                              const float* __restrict__ trans,
                                              const float* __restrict__ num,
                                              const float* __restrict__ denom,
                                              float* __restrict__ out) {
    __shared__ float Sl[LL][517];             // 43428 B
    __shared__ unsigned char pred[SS * 24];   // 12288 B
    __shared__ unsigned char mapL[64 * 32];   // 2048 B
    __shared__ float Tl[441];                 // 1764 B
    __shared__ int tg_s[SS];                  // 2048 B
    int tid = threadIdx.x, b = blockIdx.x;
    const float* SB = S + (size_t)b * (LL * SS);
    for (int i = tid; i < 441; i += 512) Tl[i] = trans[i];
    for (int f = tid; f < (LL * SS) / 4; f += 512) {
        float4 v = *reinterpret_cast<const float4*>(SB + 4 * f);
        int j = f >> 7, t0 = (f & 127) * 4;
        Sl[j][t0] = v.x; Sl[j][t0 + 1] = v.y; Sl[j][t0 + 2] = v.z; Sl[j][t0 + 3] = v.w;
    }
    if (b == 0 && tid < 64) {
        float llh = num[tid] - denom[tid];
        #pragma unroll
        for (int off = 32; off; off >>= 1) llh += __shfl_xor(llh, off);
        if (tid == 0) out[0] = -llh / (float)BB;
    }
    __syncthreads();

    for (int u = tid; u < 511 * LL; u += 512) {
        int t = 1 + u / LL;
        int j = u - (u / LL) * LL;
        unsigned int pj = (unsigned int)j;
        if (attn[b * SS + t] != 0) {
            float bv = Sl[0][t - 1] + Tl[j];
            unsigned int bi = 0;
            #pragma unroll
            for (int i = 1; i < LL; ++i) {
                float c = Sl[i][t - 1] + Tl[i * LL + j];
                bool g = c > bv;            // strict > : first max wins
                bv = g ? c : bv;
                bi = g ? (unsigned int)i : bi;
            }
            pj = bi;
        }
        pred[t * 24 + j] = (unsigned char)pj;
    }
    __syncthreads();

    if (tid < 64) {
        int lane = tid;
        float f = (lane < LL) ? (Sl[lane][SS - 1] + endT[lane]) : -INFF;
        float m = wmax64(f);
        unsigned long long msk = __ballot(f == m);
        int best_last = __ffsll(msk) - 1;

        int tlo = 8 * lane + 1;
        int thi = 8 * lane + 8; if (thi > 511) thi = 511;
        unsigned int BM[LL];
        #pragma unroll
        for (int s = 0; s < LL; ++s) BM[s] = s;
        for (int k = 0; k < 8; ++k) {
            int t = thi - k;
            if (t >= tlo) {
                #pragma unroll
                for (int s = 0; s < LL; ++s) BM[s] = pred[t * 24 + BM[s]];
            }
        }
        #pragma unroll
        for (int s = 0; s < LL; ++s) mapL[lane * 32 + s] = (unsigned char)BM[s];

        #pragma unroll
        for (int kk = 1; kk < 64; kk <<= 1) {
            int p = lane + kk;
            bool vld = p < 64;
            int pp = vld ? p : 0;
            unsigned int P[LL];
            #pragma unroll
            for (int s = 0; s < LL; ++s) {
                unsigned int v = mapL[pp * 32 + s];
                P[s] = vld ? v : (unsigned int)s;
            }
            unsigned int N[LL];
            #pragma unroll
            for (int s = 0; s < LL; ++s) N[s] = mapL[lane * 32 + P[s]];
            #pragma unroll
            for (int s = 0; s < LL; ++s) mapL[lane * 32 + s] = (unsigned char)N[s];
        }

        int st8 = mapL[lane * 32 + best_last];
        int nxt = __shfl(st8, lane + 1);
        int cur = (lane == 63) ? best_last : nxt;
        for (int k = 0; k < 8; ++k) {
            int t = thi - k;
            if (t >= tlo) {
                tg_s[t] = cur;
                cur = pred[t * 24 + cur];
            }
        }
        if (lane == 0) tg_s[0] = cur;
    }
    __syncthreads();

    {
        int t = tid;
        int tag = tg_s[t];
        int mk = attn[b * SS + t];
        float* o = out + 1 + ((size_t)b * SS + t) * LL;
        #pragma unroll
        for (int l = 0; l < LL; ++l) o[l] = (mk && tag == l) ? 1.f : 0.f;
    }
}

extern "C" void kernel_launch(void* const* d_in, const int* in_sizes, int n_in,
                              void* d_out, int out_size, void* d_ws, size_t ws_size,
                              hipStream_t stream) {
    const float* hidden = (const float*)d_in[0];
    const int*   attn   = (const int*)d_in[1];
    const int*   labels = (const int*)d_in[2];
    const float* W      = (const float*)d_in[3];
    const float* bias   = (const float*)d_in[4];
    const float* startT = (const float*)d_in[5];
    const float* endT   = (const float*)d_in[6];
    const float* trans  = (const float*)d_in[7];
    float* out = (float*)d_out;

    float* wsf   = (float*)d_ws;
    size_t emsz  = (size_t)BB * SS * LL;
    float* em0   = wsf;
    float* em1   = em0 + emsz;
    float* em2   = em1 + emsz;
    float* em3   = em2 + emsz;
    float* num   = em3 + emsz;
    float* denom = num + 64;
    float* Sbuf  = out + 4;                   // 16B-aligned; overwritten by k_back

    hipLaunchKernelGGL(k_emis, dim3(1024), dim3(128), 0, stream, hidden, W, bias,
                       em0, em1, em2, em3);
    hipLaunchKernelGGL(k_scan, dim3(192), dim3(64),  0, stream, em0, em1, em2, em3,
                       attn, labels, startT, endT, trans, num, denom, Sbuf);
    hipLaunchKernelGGL(k_back, dim3(64),  dim3(512), 0, stream, Sbuf, attn, endT, trans,
                       num, denom, out);
}